// Round 7
// baseline (386.776 us; speedup 1.0000x reference)
//
#include <hip/hip_runtime.h>
#include <math.h>

// RegionalGNN: B=8192, NC=8, H=256, HD=1024, L=3.
// R7: (1) k_head+k_reduce fused into k_head2: grid 256, GDP-reduce into frag-order
//     LDS A-tile, barrier-free K-loop with B-frags direct from global (L2-hot).
//     (2) k_layer: 6-slot depth-5 ring (vmcnt(4)), interleaved-h acc[16] -> single
//     LN pass (no 32KB stash), pairwise 1KB/wave score stash. LDS 77->67.5KB.

typedef short bf16x8 __attribute__((ext_vector_type(8)));
typedef float f32x4  __attribute__((ext_vector_type(4)));

__device__ __forceinline__ float bflo(unsigned int u){ return __uint_as_float(u << 16); }
__device__ __forceinline__ float bfhi(unsigned int u){ return __uint_as_float(u & 0xffff0000u); }
__device__ __forceinline__ float bfs(short s){ return __uint_as_float((unsigned int)(unsigned short)s << 16); }
__device__ __forceinline__ unsigned short f2bf(float f){
  unsigned int u = __float_as_uint(f);
  u += 0x7fffu + ((u >> 16) & 1u);          // RNE
  return (unsigned short)(u >> 16);
}
__device__ __forceinline__ void unpack8(uint4 a, float* o){
  o[0]=bflo(a.x); o[1]=bfhi(a.x); o[2]=bflo(a.y); o[3]=bfhi(a.y);
  o[4]=bflo(a.z); o[5]=bfhi(a.z); o[6]=bflo(a.w); o[7]=bfhi(a.w);
}
__device__ __forceinline__ uint4 pack8(const float* v){
  uint4 r;
  r.x = (unsigned int)f2bf(v[0]) | ((unsigned int)f2bf(v[1]) << 16);
  r.y = (unsigned int)f2bf(v[2]) | ((unsigned int)f2bf(v[3]) << 16);
  r.z = (unsigned int)f2bf(v[4]) | ((unsigned int)f2bf(v[5]) << 16);
  r.w = (unsigned int)f2bf(v[6]) | ((unsigned int)f2bf(v[7]) << 16);
  return r;
}
__device__ __forceinline__ void gload16(const void* g, void* l){
  __builtin_amdgcn_global_load_lds(
      (const __attribute__((address_space(1))) unsigned int*)g,
      (__attribute__((address_space(3))) unsigned int*)l, 16, 0, 0);
}
__device__ __forceinline__ bf16x8 shfl8(bf16x8 v, int src){
  union U { bf16x8 h; int u[4]; };
  U a, r; a.h = v;
  #pragma unroll
  for (int j = 0; j < 4; j++) r.u[j] = __shfl(a.u[j], src);
  return r.h;
}
__device__ __forceinline__ bf16x8 pk8(const float* v){
  bf16x8 r;
  #pragma unroll
  for (int j = 0; j < 8; j++) r[j] = (short)f2bf(v[j]);
  return r;
}

// ---------------- convert f32 -> bf16 (rf, Wq, Wk, Wv) ----------------
struct CvP { const float* src[4]; short* dst[4]; int boff[5]; };
__global__ __launch_bounds__(256) void k_convert(CvP p){
  int bid = blockIdx.x, s = 0;
  while (bid >= p.boff[s+1]) s++;
  size_t e = (size_t)(bid - p.boff[s]) * 2048 + (size_t)threadIdx.x * 8;
  const float* src = p.src[s] + e;
  float4 v0 = *(const float4*)src;
  float4 v1 = *(const float4*)(src + 4);
  float v[8] = {v0.x,v0.y,v0.z,v0.w,v1.x,v1.y,v1.z,v1.w};
  *(uint4*)(p.dst[s] + e) = pack8(v);
}

// ---------------- transpose + convert (Wi, Wo x3, Wp) ----------------
struct TrP { const float* src[5]; short* dst[5]; int rows[5]; int cols[5]; int toff[6]; };
__global__ __launch_bounds__(256) void k_transpose(TrP p){
  __shared__ float tile[64][65];
  int bid = blockIdx.x, s = 0;
  while (bid >= p.toff[s+1]) s++;
  int ti = bid - p.toff[s];
  int cols = p.cols[s], rows = p.rows[s];
  int ntc = cols >> 6;
  int r0 = (ti / ntc) * 64, c0 = (ti % ntc) * 64;
  const float* src = p.src[s];
  int row = threadIdx.x >> 2, jb = (threadIdx.x & 3) * 16;
  #pragma unroll
  for (int j = 0; j < 16; j += 4){
    float4 v = *(const float4*)(src + (size_t)(r0 + row) * cols + c0 + jb + j);
    tile[row][jb+j] = v.x; tile[row][jb+j+1] = v.y; tile[row][jb+j+2] = v.z; tile[row][jb+j+3] = v.w;
  }
  __syncthreads();
  short* dst = p.dst[s];
  float tmp[16];
  #pragma unroll
  for (int j = 0; j < 16; j++) tmp[j] = tile[jb + j][row];
  #pragma unroll
  for (int j = 0; j < 16; j += 8)
    *(uint4*)(dst + (size_t)(c0 + row) * rows + r0 + jb + j) = pack8(&tmp[j]);
}

// ---------------- bias-fold vectors via bf16 row-dots ----------------
__global__ __launch_bounds__(256) void k_vecs2(
    const short* Wqb, const short* Wkb, const short* WoTb,
    const float* bq, const float* bk, const float* bv, const float* bo,
    float* cq, float* ck, float* cvo, float* c0){
  const int job = blockIdx.x, l = blockIdx.y, tid = threadIdx.x;
  __shared__ float sv[1024];
  __shared__ float red[256];
  if (job == 3){
    float pp = 0.f;
    #pragma unroll
    for (int i = 0; i < 4; i++){
      int d = tid*4 + i;
      pp = fmaf(bq[l*1024 + d], bk[l*1024 + d], pp);
    }
    red[tid] = pp; __syncthreads();
    for (int o = 128; o > 0; o >>= 1){ if (tid < o) red[tid] += red[tid + o]; __syncthreads(); }
    if (tid == 0) c0[l] = red[0] * 0.0625f;
    return;
  }
  const short* rows = (job==0 ? Wqb : job==1 ? Wkb : WoTb) + (size_t)l*262144;
  const float* vecg = (job==0 ? bk : job==1 ? bq : bv) + l*1024;
  const float scale = (job == 2) ? 1.0f : 0.0625f;
  for (int i = tid; i < 1024; i += 256) sv[i] = vecg[i];
  __syncthreads();
  const int row = tid >> 3, sub = tid & 7;
  for (int pass = 0; pass < 8; pass++){
    int r = pass*32 + row;
    const short* rp = rows + (size_t)r*1024;
    float acc = 0.f;
    #pragma unroll
    for (int i = 0; i < 16; i++){
      int d = sub*8 + i*64;
      uint4 v = *(const uint4*)(rp + d);
      float f[8]; unpack8(v, f);
      #pragma unroll
      for (int j = 0; j < 8; j++) acc = fmaf(f[j], sv[d + j], acc);
    }
    acc += __shfl_xor(acc, 1); acc += __shfl_xor(acc, 2); acc += __shfl_xor(acc, 4);
    if (sub == 0){
      float o = acc * scale;
      if (job == 2) o += bo[l*256 + r];
      (job==0 ? cq : job==1 ? ck : cvo)[l*256 + r] = o;
    }
  }
}

// ---------------- 128x128 MFMA GEMM (precompute + input projection) ----------------
struct GDesc { const short* A; const short* Bt; short* C; int K; float scale; };
struct GemmP { GDesc d[6]; const float* bi; const float* emb; short* X; };
template<int MODE>
__global__ __launch_bounds__(256) void k_gemm128(GemmP p){
  GDesc g = p.d[blockIdx.z];
  const int tid = threadIdx.x, lane = tid & 63, w = tid >> 6;
  const int wm = w >> 1, wn = w & 1;
  __shared__ alignas(16) short As[128*32];
  __shared__ alignas(16) short Bs[128*32];
  __shared__ float s_bi[256];
  __shared__ float s_emb[2048];
  if constexpr (MODE == 1){
    s_bi[tid] = p.bi[tid];
    for (int i = tid; i < 2048; i += 256) s_emb[i] = p.emb[i];
  }
  const int K = g.K;
  const short* Ab = g.A + (size_t)blockIdx.x * 128 * K;
  const short* Bb = g.Bt + (size_t)blockIdx.y * 128 * K;
  f32x4 acc[4][4] = {};
  for (int k0 = 0; k0 < K; k0 += 32){
    #pragma unroll
    for (int i = 0; i < 2; i++){
      int s = w*2 + i;
      int ro = (s >> 2)*64 + (s & 3)*16 + (lane & 15);
      int co = k0 + (lane >> 4) * 8;
      gload16(Ab + (size_t)ro * K + co, &As[s*512]);
      gload16(Bb + (size_t)ro * K + co, &Bs[s*512]);
    }
    __syncthreads();
    bf16x8 av[4], bv[4];
    #pragma unroll
    for (int mi = 0; mi < 4; mi++)
      av[mi] = *(const bf16x8*)&As[((wm*4 + mi)*64 + lane)*8];
    #pragma unroll
    for (int nj = 0; nj < 4; nj++)
      bv[nj] = *(const bf16x8*)&Bs[((wn*4 + nj)*64 + lane)*8];
    #pragma unroll
    for (int mi = 0; mi < 4; mi++)
      #pragma unroll
      for (int nj = 0; nj < 4; nj++)
        acc[mi][nj] = __builtin_amdgcn_mfma_f32_16x16x32_bf16(av[mi], bv[nj], acc[mi][nj], 0, 0, 0);
    __syncthreads();
  }
  if constexpr (MODE == 0){
    const int ldc = gridDim.y * 128;
    #pragma unroll
    for (int mi = 0; mi < 4; mi++)
      #pragma unroll
      for (int nj = 0; nj < 4; nj++){
        int rm0 = blockIdx.x*128 + wm*64 + mi*16 + (lane >> 4) * 4;
        int cn  = blockIdx.y*128 + wn*64 + nj*16 + (lane & 15);
        #pragma unroll
        for (int j = 0; j < 4; j++)
          g.C[(size_t)(rm0 + j) * ldc + cn] = (short)f2bf(acc[mi][nj][j] * g.scale);
      }
  } else {
    #pragma unroll
    for (int mi = 0; mi < 4; mi++)
      #pragma unroll
      for (int nj = 0; nj < 4; nj++){
        int rm0 = blockIdx.x*128 + wm*64 + mi*16 + (lane >> 4) * 4;
        int cn  = blockIdx.y*128 + wn*64 + nj*16 + (lane & 15);
        #pragma unroll
        for (int j = 0; j < 4; j++){
          float base = acc[mi][nj][j] + s_bi[cn];
          #pragma unroll
          for (int c = 0; c < 8; c++)
            p.X[((size_t)(rm0 + j) * 8 + c) * 256 + cn] = (short)f2bf(base + s_emb[c*256 + cn]);
        }
      }
  }
}

// ---------------- fused layer (R7) ----------------
// Block = 16 batches (128 rows), wave = batch-pair. X in regs (A-frag layout).
// 32 weight panels (Wqk/Wvo x h x kk) through 6-slot ring, depth-5, vmcnt(4).
// acc[16] holds BOTH N-halves (interleaved h) -> single LN epilogue, no stash.
__global__ __launch_bounds__(512, 4) void k_layer(short* __restrict__ Xg,
    const short* __restrict__ Wqk, const short* __restrict__ Wvo,
    const float* __restrict__ ckp, const float* __restrict__ cvop,
    const float* __restrict__ gp, const float* __restrict__ bp){
  const int tid = threadIdx.x, lane = tid & 63, w = tid >> 6;
  __shared__ alignas(16) short pan[6][4096];   // 48 KB ring
  __shared__ alignas(16) short tst[8][512];    // 8 KB: 1KB/wave score stash
  __shared__ alignas(16) float atn[8][16][16]; // 8 KB attention probs
  __shared__ short ckb[256];
  __shared__ float s_add[256], s_g[256], s_b[256];
  const int r0 = blockIdx.x * 128;
  const int dsub = (lane >> 4) * 8;

  #define VMW(n) asm volatile("s_waitcnt vmcnt(" #n ")" ::: "memory")
  #define LKW    asm volatile("s_waitcnt lgkmcnt(0)" ::: "memory")
  #define BAR    __builtin_amdgcn_s_barrier()

  // X rows -> registers: lane holds X[row = pair*16 + (lane&15)][dsub + e + 32c]
  bf16x8 xf[8];
  { const short* xp = Xg + (size_t)(r0 + w*16 + (lane & 15)) * 256 + dsub;
    #pragma unroll
    for (int c = 0; c < 8; c++) xf[c] = *(const bf16x8*)(xp + c*32); }
  if (tid < 256){
    ckb[tid]   = (short)f2bf(ckp[tid]);
    s_add[tid] = cvop[tid]; s_g[tid] = gp[tid]; s_b[tid] = bp[tid];
  }

  auto STAGE = [&](int i){
    const short* W = (i < 16) ? Wqk : Wvo;
    const int loc = i & 15, h = loc & 1, kk = loc >> 1;
    const short* src = W + (size_t)(h*128 + w*16 + (lane & 15)) * 256 + kk*32 + dsub;
    gload16(src, &pan[i % 6][w * 512]);
  };
  STAGE(0); STAGE(1); STAGE(2); STAGE(3); STAGE(4);
  LKW;   // publish ckb/s_* before first barrier

  f32x4 A16[16];
  #pragma unroll
  for (int a = 0; a < 16; a++) A16[a] = (f32x4){0.f,0.f,0.f,0.f};

  auto STEP = [&](int i, bf16x8* AF){
    if (i <= 27) { VMW(4); } else if (i == 28) { VMW(3); }
    else if (i == 29) { VMW(2); } else if (i == 30) { VMW(1); } else { VMW(0); }
    BAR;
    if (i + 5 <= 31) STAGE(i + 5);
    const short* P = pan[i % 6];
    const int loc = i & 15, h = loc & 1, kk = loc >> 1;
    #pragma unroll
    for (int nj = 0; nj < 8; nj++){
      bf16x8 bv = *(const bf16x8*)&P[(nj*64 + lane)*8];
      A16[h*8 + nj] = __builtin_amdgcn_mfma_f32_16x16x32_bf16(AF[kk], bv, A16[h*8+nj], 0, 0, 0);
    }
  };

  // ===== GEMM1: T = X @ Wqk, both halves into A16 =====
  #pragma unroll
  for (int i = 0; i < 16; i++) STEP(i, xf);

  // ===== scores: sacc += mfma(T-chunk, X-chunk) over 8 d-chunks =====
  f32x4 sacc = {0.f, 0.f, 0.f, 0.f};
  #pragma unroll
  for (int cl = 0; cl < 8; cl++){
    const int a0 = (cl >> 2)*8 + 2*(cl & 3);
    #pragma unroll
    for (int t = 0; t < 2; t++)
      #pragma unroll
      for (int jj = 0; jj < 4; jj++){
        int dloc = t*16 + (lane & 15), i_ = (lane >> 4)*4 + jj;
        tst[w][(dloc >> 3)*128 + i_*8 + (dloc & 7)] = (short)f2bf(A16[a0 + t][jj]);
      }
    LKW; __builtin_amdgcn_sched_barrier(0);
    bf16x8 tf = *(const bf16x8*)&tst[w][(lane >> 4)*128 + (lane & 15)*8];
    sacc = __builtin_amdgcn_mfma_f32_16x16x32_bf16(tf, xf[cl], sacc, 0, 0, 0);
  }

  // ===== skv[m] = X[m].ck (m = lane&15) =====
  float skv = 0.f;
  #pragma unroll
  for (int c = 0; c < 8; c++){
    bf16x8 cv = *(const bf16x8*)&ckb[c*32 + dsub];
    #pragma unroll
    for (int e = 0; e < 8; e++) skv = fmaf(bfs(xf[c][e]), bfs(cv[e]), skv);
  }
  skv += __shfl_xor(skv, 16); skv += __shfl_xor(skv, 32);

  // ===== softmax (C-layout) =====
  {
    const unsigned long long MASK64 = 0x02191D69752B857EULL;   // ADJ[n][m] at bit n*8+m
    #pragma unroll
    for (int jj = 0; jj < 4; jj++){
      int i_ = (lane >> 4)*4 + jj, j_ = lane & 15;
      bool ok = (((i_ ^ j_) & 8) == 0) &&
                ((MASK64 >> (((i_ & 7) << 3) | (j_ & 7))) & 1ull);
      float sv = ok ? (sacc[jj] + skv) : -3.0e38f;
      float mx = sv;
      mx = fmaxf(mx, __shfl_xor(mx, 1));
      mx = fmaxf(mx, __shfl_xor(mx, 2));
      mx = fmaxf(mx, __shfl_xor(mx, 4));
      float e = ok ? __expf(sv - mx) : 0.f;
      float sum = e;
      sum += __shfl_xor(sum, 1); sum += __shfl_xor(sum, 2); sum += __shfl_xor(sum, 4);
      atn[w][i_][j_] = e / sum;
    }
  }
  LKW;   // own-wave atn writes -> reads

  // ===== PV: y A-frags via shfl from X regs =====
  bf16x8 yfrag[8];
  {
    float4 A0 = *(const float4*)&atn[w][lane & 15][lane & 8];
    float4 A1 = *(const float4*)&atn[w][lane & 15][(lane & 8) + 4];
    float am[8] = {A0.x, A0.y, A0.z, A0.w, A1.x, A1.y, A1.z, A1.w};
    #pragma unroll
    for (int c = 0; c < 8; c++){
      float a8[8] = {0,0,0,0,0,0,0,0};
      #pragma unroll
      for (int mi = 0; mi < 8; mi++){
        bf16x8 xs = shfl8(xf[c], (lane & 48) | (lane & 8) | mi);
        #pragma unroll
        for (int e = 0; e < 8; e++) a8[e] = fmaf(am[mi], bfs(xs[e]), a8[e]);
      }
      yfrag[c] = pk8(a8);
    }
  }

  // ===== GEMM2: out = y @ Wvo, both halves into A16 =====
  #pragma unroll
  for (int a = 0; a < 16; a++) A16[a] = (f32x4){0.f,0.f,0.f,0.f};
  #pragma unroll
  for (int i = 16; i < 32; i++) STEP(i, yfrag);

  // ===== epilogue: +cvo +residual, LN, write (single pass, wave-local rows) =====
  #pragma unroll
  for (int jj = 0; jj < 4; jj++){
    const int i_ = (lane >> 4)*4 + jj;
    const size_t rb = (size_t)(r0 + w*16 + i_) * 256;
    float ps = 0.f, pq = 0.f;
    #pragma unroll
    for (int a = 0; a < 16; a++){
      int n = (a >> 3)*128 + (a & 7)*16 + (lane & 15);
      unsigned short rv = *(const unsigned short*)(Xg + rb + n);
      float t = A16[a][jj] + s_add[n] + __uint_as_float((unsigned int)rv << 16);
      A16[a][jj] = t;
      ps += t; pq = fmaf(t, t, pq);
    }
    ps += __shfl_xor(ps, 1); ps += __shfl_xor(ps, 2);
    ps += __shfl_xor(ps, 4); ps += __shfl_xor(ps, 8);
    pq += __shfl_xor(pq, 1); pq += __shfl_xor(pq, 2);
    pq += __shfl_xor(pq, 4); pq += __shfl_xor(pq, 8);
    float mean_ = ps * (1.f/256.f);
    float var_  = pq * (1.f/256.f) - mean_ * mean_;
    float rst_  = rsqrtf(fmaxf(var_, 0.f) + 1e-5f);
    #pragma unroll
    for (int a = 0; a < 16; a++){
      int n = (a >> 3)*128 + (a & 7)*16 + (lane & 15);
      float yv = (A16[a][jj] - mean_) * rst_ * s_g[n] + s_b[n];
      *(unsigned short*)(Xg + rb + n) = f2bf(yv);
    }
  }
  #undef VMW
  #undef LKW
  #undef BAR
}

// ---------------- head (R7): GDP-reduce + GEMM + LN + GELU, barrier-light ----------------
// grid 256, 256 thr (4 waves). A[32x256] built in frag-order LDS (GDP-fused);
// B-frags read per-lane directly from global (WpT 128KB, L2-hot). No K-loop barriers.
__global__ __launch_bounds__(256) void k_head2(const short* __restrict__ X,
    const short* __restrict__ Bt, const float* __restrict__ addv,
    const float* __restrict__ gv, const float* __restrict__ bv2,
    float* __restrict__ outp){
  const int tid = threadIdx.x, lane = tid & 63, w = tid >> 6;
  __shared__ alignas(16) short Afr[16*512];    // 16 KB frag-order A
  __shared__ float redS[4][32], redQ[4][32];
  __shared__ float s_add[256], s_g[256], s_b[256];
  __shared__ float s_mean[32], s_rstd[32];
  s_add[tid] = addv[tid]; s_g[tid] = gv[tid]; s_b[tid] = bv2[tid];
  const int r0 = blockIdx.x * 32;
  // GDP-reduce -> frag-order A (each thread: 1 row x 32 cols)
  {
    const float GDPc[8] = {0.4f,0.15f,0.12f,0.1f,0.08f,0.08f,0.05f,0.02f};
    int row = tid >> 3, kk = tid & 7;
    const short* xr = X + ((size_t)(r0 + row) * 8) * 256 + kk*32;
    float v[32];
    #pragma unroll
    for (int j = 0; j < 32; j++) v[j] = 0.f;
    #pragma unroll
    for (int c = 0; c < 8; c++){
      #pragma unroll
      for (int q = 0; q < 4; q++){
        uint4 xv = *(const uint4*)(xr + (size_t)c*256 + q*8);
        float xfv[8]; unpack8(xv, xfv);
        #pragma unroll
        for (int j = 0; j < 8; j++) v[q*8 + j] = fmaf(GDPc[c], xfv[j], v[q*8 + j]);
      }
    }
    #pragma unroll
    for (int q = 0; q < 4; q++)
      *(uint4*)&Afr[((row >> 4)*8 + kk)*512 + ((row & 15) + 16*q)*8] = pack8(&v[q*8]);
  }
  __syncthreads();
  // K-loop: A from LDS, B direct-global (no barriers)
  f32x4 acc[2][4] = {};
  #pragma unroll
  for (int kk = 0; kk < 8; kk++){
    bf16x8 av0 = *(const bf16x8*)&Afr[(0*8 + kk)*512 + lane*8];
    bf16x8 av1 = *(const bf16x8*)&Afr[(1*8 + kk)*512 + lane*8];
    #pragma unroll
    for (int nj = 0; nj < 4; nj++){
      const short* gb = Bt + (size_t)(w*64 + nj*16 + (lane & 15))*256 + kk*32 + (lane >> 4)*8;
      bf16x8 bv = *(const bf16x8*)gb;
      acc[0][nj] = __builtin_amdgcn_mfma_f32_16x16x32_bf16(av0, bv, acc[0][nj], 0, 0, 0);
      acc[1][nj] = __builtin_amdgcn_mfma_f32_16x16x32_bf16(av1, bv, acc[1][nj], 0, 0, 0);
    }
  }
  // bias + stats
  #pragma unroll
  for (int s = 0; s < 2; s++)
    #pragma unroll
    for (int jj = 0; jj < 4; jj++){
      int rl = s*16 + (lane >> 4)*4 + jj;
      float ps = 0.f, pq = 0.f;
      #pragma unroll
      for (int nj = 0; nj < 4; nj++){
        int c = w*64 + nj*16 + (lane & 15);
        float t = acc[s][nj][jj] + s_add[c];
        acc[s][nj][jj] = t;
        ps += t; pq = fmaf(t, t, pq);
      }
      ps += __shfl_xor(ps, 1); pq += __shfl_xor(pq, 1);
      ps += __shfl_xor(ps, 2); pq += __shfl_xor(pq, 2);
      ps += __shfl_xor(ps, 4); pq += __shfl_xor(pq, 4);
      ps += __shfl_xor(ps, 8); pq += __shfl_xor(pq, 8);
      if ((lane & 15) == 0){ redS[w][rl] = ps; redQ[w][rl] = pq; }
    }
  __syncthreads();
  if (tid < 32){
    float sm = redS[0][tid] + redS[1][tid] + redS[2][tid] + redS[3][tid];
    float sq = redQ[0][tid] + redQ[1][tid] + redQ[2][tid] + redQ[3][tid];
    float mean = sm * (1.f/256.f);
    float var  = sq * (1.f/256.f) - mean * mean;
    s_mean[tid] = mean;
    s_rstd[tid] = rsqrtf(fmaxf(var, 0.f) + 1e-5f);
  }
  __syncthreads();
  #pragma unroll
  for (int s = 0; s < 2; s++)
    #pragma unroll
    for (int jj = 0; jj < 4; jj++){
      int rl = s*16 + (lane >> 4)*4 + jj;
      float mean = s_mean[rl], rstd = s_rstd[rl];
      #pragma unroll
      for (int nj = 0; nj < 4; nj++){
        int c = w*64 + nj*16 + (lane & 15);
        float y = (acc[s][nj][jj] - mean) * rstd * s_g[c] + s_b[c];
        outp[(size_t)(r0 + rl) * 256 + c] = 0.5f * y * (1.0f + erff(y * 0.70710678118654752f));
      }
    }
}

extern "C" void kernel_launch(void* const* d_in, const int* in_sizes, int n_in,
                              void* d_out, int out_size, void* d_ws, size_t ws_size,
                              hipStream_t stream){
  (void)in_sizes; (void)n_in; (void)out_size; (void)ws_size;
  const float* rf  = (const float*)d_in[0];
  const float* Wi  = (const float*)d_in[1];
  const float* bi  = (const float*)d_in[2];
  const float* emb = (const float*)d_in[3];
  const float* Wq  = (const float*)d_in[4];
  const float* bq  = (const float*)d_in[5];
  const float* Wk  = (const float*)d_in[6];
  const float* bk  = (const float*)d_in[7];
  const float* Wv  = (const float*)d_in[8];
  const float* bv  = (const float*)d_in[9];
  const float* Wo  = (const float*)d_in[10];
  const float* bo  = (const float*)d_in[11];
  const float* lng = (const float*)d_in[12];
  const float* lnb = (const float*)d_in[13];
  const float* Wp  = (const float*)d_in[14];
  const float* bp  = (const float*)d_in[15];
  const float* lpg = (const float*)d_in[16];
  const float* lpb = (const float*)d_in[17];

  char* ws = (char*)d_ws;
  short* X    = (short*)(ws);                      // [65536][256] bf16
  // transient weight copies (consumed before X written)
  short* Wqb  = (short*)(ws);
  short* Wkb  = (short*)(ws + 1572864ull);
  short* Wvb  = (short*)(ws + 3145728ull);
  short* WoTb = (short*)(ws + 4718592ull);
  short* rfb  = (short*)(ws + 33554432ull);        // [8192][512] bf16 (pre-input GEMM)
  // persistent tail
  short* WiTb = (short*)(ws + 67108864ull);
  short* WpTb = (short*)(ws + 67371008ull);
  short* Wqk  = (short*)(ws + 67502080ull);        // [3][256][256] Bt, pre-scaled 1/16
  short* Wvo  = (short*)(ws + 67895296ull);        // [3][256][256] Bt
  float* cqv  = (float*)(ws + 68288512ull);
  float* ckv  = (float*)(ws + 68291584ull);
  float* cvov = (float*)(ws + 68294656ull);
  float* c0v  = (float*)(ws + 68297728ull);

  { CvP cv;
    cv.src[0]=rf; cv.dst[0]=rfb;
    cv.src[1]=Wq; cv.dst[1]=Wqb;
    cv.src[2]=Wk; cv.dst[2]=Wkb;
    cv.src[3]=Wv; cv.dst[3]=Wvb;
    cv.boff[0]=0; cv.boff[1]=2048; cv.boff[2]=2432; cv.boff[3]=2816; cv.boff[4]=3200;
    k_convert<<<dim3(3200), dim3(256), 0, stream>>>(cv); }

  { TrP tp;
    tp.src[0]=Wi;          tp.dst[0]=WiTb;          tp.rows[0]=512;  tp.cols[0]=256;
    tp.src[1]=Wo;          tp.dst[1]=WoTb;          tp.rows[1]=1024; tp.cols[1]=256;
    tp.src[2]=Wo+262144;   tp.dst[2]=WoTb+262144;   tp.rows[2]=1024; tp.cols[2]=256;
    tp.src[3]=Wo+524288;   tp.dst[3]=WoTb+524288;   tp.rows[3]=1024; tp.cols[3]=256;
    tp.src[4]=Wp;          tp.dst[4]=WpTb;          tp.rows[4]=256;  tp.cols[4]=256;
    tp.toff[0]=0; tp.toff[1]=32; tp.toff[2]=96; tp.toff[3]=160; tp.toff[4]=224; tp.toff[5]=240;
    k_transpose<<<dim3(240), dim3(256), 0, stream>>>(tp); }

  k_vecs2<<<dim3(4, 3), dim3(256), 0, stream>>>(Wqb, Wkb, WoTb, bq, bk, bv, bo,
                                                cqv, ckv, cvov, c0v);

  { GemmP g{};
    for (int l = 0; l < 3; l++){
      g.d[l]   = GDesc{ Wkb  + l*262144, Wqb + l*262144, Wqk + l*65536, 1024, 0.0625f };
      g.d[3+l] = GDesc{ WoTb + l*262144, Wvb + l*262144, Wvo + l*65536, 1024, 1.0f };
    }
    k_gemm128<0><<<dim3(2,2,6), dim3(256), 0, stream>>>(g); }

  { GemmP g{};   // X[b,c,:] = rf@Wi + bi + emb[c]
    g.d[0] = GDesc{ rfb, WiTb, X, 512, 1.0f };
    g.bi = bi; g.emb = emb; g.X = X;
    k_gemm128<1><<<dim3(64,2,1), dim3(256), 0, stream>>>(g); }

  for (int l = 0; l < 3; l++)
    k_layer<<<dim3(512), dim3(512), 0, stream>>>(X, Wqk + l*65536, Wvo + l*65536,
        ckv + l*256, cvov + l*256, lng + l*256, lnb + l*256);

  k_head2<<<dim3(256), dim3(256), 0, stream>>>(X, WpTb, bp, lpg, lpb, (float*)d_out);
}